// Round 1
// baseline (452.725 us; speedup 1.0000x reference)
//
#include <hip/hip_runtime.h>
#include <hip/hip_bf16.h>

// Reference returns (input0, input1) unchanged — the vmap'd scan is dead code.
// d_out = concat(input0.flat, input1.flat), each 2048*65536 f32 elements.
// Pure memory-bound copy: 1 GiB in + 1 GiB out => ~340 us at 6.3 TB/s.

__global__ __launch_bounds__(256) void concat_copy_kernel(
    const float4* __restrict__ a,
    const float4* __restrict__ b,
    float4* __restrict__ out,
    long n4) {  // n4 = float4 count per input
    long tid = (long)blockIdx.x * blockDim.x + threadIdx.x;
    long stride = (long)gridDim.x * blockDim.x;
    for (long k = tid; k < n4; k += stride) {
        out[k] = a[k];
    }
    for (long k = tid; k < n4; k += stride) {
        out[n4 + k] = b[k];
    }
}

extern "C" void kernel_launch(void* const* d_in, const int* in_sizes, int n_in,
                              void* d_out, int out_size, void* d_ws, size_t ws_size,
                              hipStream_t stream) {
    const float* in0 = (const float*)d_in[0];
    const float* in1 = (const float*)d_in[1];
    float* out = (float*)d_out;

    long n = (long)in_sizes[0];       // 2048*65536 = 134217728, divisible by 4
    long n4 = n / 4;                  // 33554432 float4 per input

    const int block = 256;
    const int grid = 2048;            // 256 CUs * 8 blocks/CU, grid-stride the rest

    concat_copy_kernel<<<grid, block, 0, stream>>>(
        (const float4*)in0, (const float4*)in1, (float4*)out, n4);
}